// Round 8
// baseline (214.628 us; speedup 1.0000x reference)
//
#include <hip/hip_runtime.h>
#include <hip/hip_bf16.h>

#define NB  8
#define NC  256
#define NCK 64
#define SEQ 2048

typedef unsigned short u16;
typedef short bfrag8 __attribute__((ext_vector_type(8)));   // 8 bf16 (4 VGPRs)
typedef float ffrag4 __attribute__((ext_vector_type(4)));   // 4 fp32 acc

#define MFMA16(a, b, c) __builtin_amdgcn_mfma_f32_16x16x32_bf16((a), (b), (c), 0, 0, 0)

static __device__ __forceinline__ u16 f2bf(float f) {
  return __builtin_bit_cast(u16, (__bf16)f);  // RNE
}
static __device__ __forceinline__ float bf2f(u16 u) {
  unsigned v = (unsigned)u << 16;
  return __builtin_bit_cast(float, v);
}

// ---------- W fp32 -> bf16 hi/lo for Wv, Wt; tail blocks zero ssum/sqsum, rowsum_g ----------
__global__ __launch_bounds__(256) void wconv_kernel(
    const float* __restrict__ Wv, const float* __restrict__ Wt,
    u16* __restrict__ dst, float* __restrict__ zz, float* __restrict__ rowsum_g) {
  int bx = blockIdx.x;
  if (bx >= 512) {
    if (bx == 512) {
      zz[threadIdx.x] = 0.f;
      zz[256 + threadIdx.x] = 0.f;
    } else {
      rowsum_g[(bx - 513) * 256 + threadIdx.x] = 0.f;
    }
    return;
  }
  int id = bx * 256 + threadIdx.x;
  const float* src;
  int off;
  if (id < 65536) { src = Wv; off = 131072; }
  else            { src = Wt; off = 262144; id -= 65536; }
  float v = src[id];
  u16 h = f2bf(v);
  u16 l = f2bf(v - bf2f(h));
  dst[off + id] = h;
  dst[off + 65536 + id] = l;
}

// ---------- transpose-convert: in fp32 [b][CIN][n] -> Thi/Tlo bf16 [b][n][CIN] ----------
template <int CIN>
__global__ __launch_bounds__(256) void tconv_kernel(
    const float* __restrict__ in, u16* __restrict__ Thi, u16* __restrict__ Tlo) {
  __shared__ float t[32][33];
  const int tid = threadIdx.x;
  const int b = blockIdx.x & 7, cg = blockIdx.x >> 3;
  const int c0 = cg << 5, n0 = blockIdx.y << 5;
  {
    int c = tid >> 3, m4 = (tid & 7) << 2;
    float4 v = *(const float4*)&in[((size_t)b * CIN + c0 + c) * SEQ + n0 + m4];
    t[c][m4 + 0] = v.x; t[c][m4 + 1] = v.y; t[c][m4 + 2] = v.z; t[c][m4 + 3] = v.w;
  }
  __syncthreads();
  {
    int n = tid >> 3, c4 = (tid & 7) << 2;
    u16 h[4], l[4];
#pragma unroll
    for (int j = 0; j < 4; ++j) {
      float v = t[c4 + j][n];
      h[j] = f2bf(v);
      l[j] = f2bf(v - bf2f(h[j]));
    }
    size_t base = ((size_t)b * SEQ + n0 + n) * CIN + c0 + c4;
    *(uint2*)&Thi[base] = make_uint2((unsigned)h[0] | ((unsigned)h[1] << 16),
                                     (unsigned)h[2] | ((unsigned)h[3] << 16));
    *(uint2*)&Tlo[base] = make_uint2((unsigned)l[0] | ((unsigned)l[1] << 16),
                                     (unsigned)l[2] | ((unsigned)l[3] << 16));
  }
}

// ---------- G' = Wk^T * Wq : G'[ck][c] = sum_o Wq[o][c] * Wk[o][ck], hi/lo bf16 ----------
__global__ __launch_bounds__(256) void gcomp_kernel(
    const float* __restrict__ Wq, const float* __restrict__ Wk,
    u16* __restrict__ Gh, u16* __restrict__ Gl) {
  const int ck = blockIdx.x, c = threadIdx.x;
  float s = 0.f;
#pragma unroll 8
  for (int o = 0; o < 256; ++o) s += Wq[o * 256 + c] * Wk[o * 64 + ck];
  u16 h = f2bf(s);
  Gh[ck * 256 + c] = h;
  Gl[ck * 256 + c] = f2bf(s - bf2f(h));
}

// ---------- MFMA GEMM hi/lo split (3-pass): x_v projection, out bf16 tiled
// xv_t[b][nt=n/32][o][32n] (+bias) for coalesced PV loads in attn ----------
template <int K>
__global__ __launch_bounds__(256, 2) void gemm_kernel(
    const u16* __restrict__ Ahi, const u16* __restrict__ Alo,
    const u16* __restrict__ Whi, const u16* __restrict__ Wlo,
    const float* __restrict__ bias, u16* __restrict__ outp) {
  constexpr int SP = K + 8;
  extern __shared__ u16 lds[];  // 64*SP*2 shorts (hi rows then lo rows)
  const int tid = threadIdx.x;
  const int wv = tid >> 6, lane = tid & 63, quad = lane >> 4, ln = lane & 15;
  const int b = blockIdx.x & 7, nt = blockIdx.x >> 3;
  const int o0 = blockIdx.y << 6, n0 = nt << 7;

  constexpr int RW = K / 8;
  for (int i = tid; i < 64 * RW; i += 256) {
    int row = i / RW, kc = (i % RW) * 8;
    *(uint4*)&lds[row * SP + kc] = *(const uint4*)&Whi[(size_t)(o0 + row) * K + kc];
    *(uint4*)&lds[(64 + row) * SP + kc] = *(const uint4*)&Wlo[(size_t)(o0 + row) * K + kc];
  }
  constexpr int NA = K / 32;
  bfrag8 ahi[2][NA], alo[2][NA];
#pragma unroll
  for (int rs = 0; rs < 2; ++rs) {
    const u16* ap = Ahi + ((size_t)b * SEQ + n0 + wv * 32 + rs * 16 + ln) * K + quad * 8;
    const u16* al = Alo + ((size_t)b * SEQ + n0 + wv * 32 + rs * 16 + ln) * K + quad * 8;
#pragma unroll
    for (int a = 0; a < NA; ++a) {
      ahi[rs][a] = *(const bfrag8*)(ap + a * 32);
      alo[rs][a] = *(const bfrag8*)(al + a * 32);
    }
  }
  __syncthreads();

  ffrag4 acc[2][4];
#pragma unroll
  for (int ot = 0; ot < 4; ++ot) {
    ffrag4 e0 = {0.f, 0.f, 0.f, 0.f}, e1 = {0.f, 0.f, 0.f, 0.f};
#pragma unroll
    for (int a = 0; a < NA; ++a) {
      bfrag8 wh = *(const bfrag8*)&lds[(ot * 16 + ln) * SP + a * 32 + quad * 8];
      bfrag8 wl = *(const bfrag8*)&lds[(64 + ot * 16 + ln) * SP + a * 32 + quad * 8];
      e0 = MFMA16(wh, ahi[0][a], e0);
      e0 = MFMA16(wh, alo[0][a], e0);
      e0 = MFMA16(wl, ahi[0][a], e0);
      e1 = MFMA16(wh, ahi[1][a], e1);
      e1 = MFMA16(wh, alo[1][a], e1);
      e1 = MFMA16(wl, ahi[1][a], e1);
    }
    acc[0][ot] = e0;
    acc[1][ot] = e1;
  }
  __syncthreads();  // lds free for epilogue

  u16* tl = lds;  // [64 o][136]
#pragma unroll
  for (int rs = 0; rs < 2; ++rs)
#pragma unroll
    for (int ot = 0; ot < 4; ++ot)
#pragma unroll
      for (int r = 0; r < 4; ++r)
        tl[(ot * 16 + quad * 4 + r) * 136 + wv * 32 + rs * 16 + ln] = f2bf(acc[rs][ot][r]);
  __syncthreads();
  for (int i = tid; i < 64 * 16; i += 256) {
    int row = i >> 4, n8 = (i & 15) * 8;
    float bb = (bias != nullptr) ? bias[o0 + row] : 0.f;
    u16 pk[8];
#pragma unroll
    for (int j = 0; j < 8; ++j) pk[j] = f2bf(bf2f(tl[row * 136 + n8 + j]) + bb);
    int t = (n0 + n8) >> 5, no = n8 & 31;
    *(uint4*)&outp[(((size_t)b * 64 + t) * NC + o0 + row) * 32 + no] = *(uint4*)pk;
  }
}

// ---------- gemmxg: xg[b][n][64] = qT(hi/lo) x G'(hi/lo), 3-pass, bf16-hi out ----------
__global__ __launch_bounds__(256, 2) void gemmxg_kernel(
    const u16* __restrict__ Ahi, const u16* __restrict__ Alo,
    const u16* __restrict__ Gh, const u16* __restrict__ Gl,
    u16* __restrict__ xg) {
  constexpr int K = 256, SP = K + 8;
  __shared__ u16 lds[128 * SP];  // 67584 B: G' hi rows 0..63, lo rows 64..127
  const int tid = threadIdx.x;
  const int wv = tid >> 6, lane = tid & 63, quad = lane >> 4, ln = lane & 15;
  const int b = blockIdx.x & 7, nt = blockIdx.x >> 3;
  const int n0 = nt << 7;

  for (int i = tid; i < 64 * 32; i += 256) {
    int row = i >> 5, kc = (i & 31) * 8;
    *(uint4*)&lds[row * SP + kc] = *(const uint4*)&Gh[(size_t)row * K + kc];
    *(uint4*)&lds[(64 + row) * SP + kc] = *(const uint4*)&Gl[(size_t)row * K + kc];
  }
  bfrag8 ahi[2][8], alo[2][8];
#pragma unroll
  for (int rs = 0; rs < 2; ++rs) {
    const u16* ap = Ahi + ((size_t)b * SEQ + n0 + wv * 32 + rs * 16 + ln) * K + quad * 8;
    const u16* al = Alo + ((size_t)b * SEQ + n0 + wv * 32 + rs * 16 + ln) * K + quad * 8;
#pragma unroll
    for (int a = 0; a < 8; ++a) {
      ahi[rs][a] = *(const bfrag8*)(ap + a * 32);
      alo[rs][a] = *(const bfrag8*)(al + a * 32);
    }
  }
  __syncthreads();

  ffrag4 acc[2][4];
#pragma unroll
  for (int ot = 0; ot < 4; ++ot) {
    ffrag4 e0 = {0.f, 0.f, 0.f, 0.f}, e1 = {0.f, 0.f, 0.f, 0.f};
#pragma unroll
    for (int a = 0; a < 8; ++a) {
      bfrag8 wh = *(const bfrag8*)&lds[(ot * 16 + ln) * SP + a * 32 + quad * 8];
      bfrag8 wl = *(const bfrag8*)&lds[(64 + ot * 16 + ln) * SP + a * 32 + quad * 8];
      e0 = MFMA16(ahi[0][a], wh, e0);
      e0 = MFMA16(alo[0][a], wh, e0);
      e0 = MFMA16(ahi[0][a], wl, e0);
      e1 = MFMA16(ahi[1][a], wh, e1);
      e1 = MFMA16(alo[1][a], wh, e1);
      e1 = MFMA16(ahi[1][a], wl, e1);
    }
    acc[0][ot] = e0;
    acc[1][ot] = e1;
  }
  __syncthreads();

  u16* tl = lds;  // [128 n][72], cols 0..63 used
#pragma unroll
  for (int rs = 0; rs < 2; ++rs)
#pragma unroll
    for (int ot = 0; ot < 4; ++ot)
#pragma unroll
      for (int r = 0; r < 4; ++r)
        tl[(wv * 32 + rs * 16 + quad * 4 + r) * 72 + ot * 16 + ln] = f2bf(acc[rs][ot][r]);
  __syncthreads();
  for (int i = tid; i < 128 * 8; i += 256) {
    int row = i >> 3, c8 = (i & 7) * 8;
    *(uint4*)&xg[((size_t)b * SEQ + n0 + row) * NCK + c8] = *(uint4*)&tl[row * 72 + c8];
  }
}

// ---------- rowsum: rowsum_g[b,n] += sum_m exp(e[n,m]), K=64 energy, 2-pass xT hi/lo.
// LDS-staged, double-buffered (R3 structure). ----------
__global__ __launch_bounds__(256, 2) void rowsum_kernel(
    const u16* __restrict__ xg, const u16* __restrict__ xTh,
    const u16* __restrict__ xTl, float* __restrict__ rowsum_g) {
  __shared__ u16 bk_l[2][2][64 * 76];  // [dbuf][hi/lo], 4 x 9728 B
  const int tid = threadIdx.x;
  const int wv = tid >> 6, lane = tid & 63, quad = lane >> 4, ln = lane & 15;
  const int b  = blockIdx.x & 7;
  const int nt = (blockIdx.x >> 3) & 15;
  const int mh = blockIdx.x >> 7;   // 0..3
  const int n0 = nt << 7;
  const int m0 = mh << 9;

  bfrag8 aq[2][2];
#pragma unroll
  for (int rs = 0; rs < 2; ++rs) {
    const u16* qp = xg + ((size_t)b * SEQ + n0 + wv * 32 + rs * 16 + ln) * NCK + quad * 8;
    aq[rs][0] = *(const bfrag8*)qp;
    aq[rs][1] = *(const bfrag8*)(qp + 32);
  }

  const int srow = tid >> 2, scol = (tid & 3) << 4;
  uint4 ph0, ph1, pl0, pl1;
  {
    size_t base = ((size_t)b * SEQ + m0 + srow) * NCK + scol;
    ph0 = *(const uint4*)&xTh[base];     ph1 = *(const uint4*)&xTh[base + 8];
    pl0 = *(const uint4*)&xTl[base];     pl1 = *(const uint4*)&xTl[base + 8];
  }

  float rsum[2][4];
#pragma unroll
  for (int rs = 0; rs < 2; ++rs)
#pragma unroll
    for (int r = 0; r < 4; ++r) rsum[rs][r] = 0.f;

  for (int ch = 0; ch < 8; ++ch) {
    u16* bh = &bk_l[ch & 1][0][srow * 76 + scol];
    u16* bl = &bk_l[ch & 1][1][srow * 76 + scol];
    *(uint4*)bh = ph0; *(uint4*)(bh + 8) = ph1;
    *(uint4*)bl = pl0; *(uint4*)(bl + 8) = pl1;
    if (ch < 7) {
      size_t base = ((size_t)b * SEQ + m0 + (ch + 1) * 64 + srow) * NCK + scol;
      ph0 = *(const uint4*)&xTh[base];   ph1 = *(const uint4*)&xTh[base + 8];
      pl0 = *(const uint4*)&xTl[base];   pl1 = *(const uint4*)&xTl[base + 8];
    }
    __syncthreads();

    ffrag4 e[2][4];
#pragma unroll
    for (int rs = 0; rs < 2; ++rs)
#pragma unroll
      for (int ms = 0; ms < 4; ++ms) e[rs][ms] = (ffrag4){0.f, 0.f, 0.f, 0.f};
#pragma unroll
    for (int ms = 0; ms < 4; ++ms)
#pragma unroll
      for (int kk = 0; kk < 2; ++kk) {
        bfrag8 bbh = *(const bfrag8*)&bk_l[ch & 1][0][(ms * 16 + ln) * 76 + kk * 32 + quad * 8];
        bfrag8 bbl = *(const bfrag8*)&bk_l[ch & 1][1][(ms * 16 + ln) * 76 + kk * 32 + quad * 8];
        // op order per accumulator must match attn_kernel exactly: kk0h,kk0l,kk1h,kk1l
        e[0][ms] = MFMA16(aq[0][kk], bbh, e[0][ms]);
        e[0][ms] = MFMA16(aq[0][kk], bbl, e[0][ms]);
        e[1][ms] = MFMA16(aq[1][kk], bbh, e[1][ms]);
        e[1][ms] = MFMA16(aq[1][kk], bbl, e[1][ms]);
      }
#pragma unroll
    for (int rs = 0; rs < 2; ++rs)
#pragma unroll
      for (int ms = 0; ms < 4; ++ms)
#pragma unroll
        for (int r = 0; r < 4; ++r) rsum[rs][r] += __expf(e[rs][ms][r]);
  }

#pragma unroll
  for (int msk = 1; msk < 16; msk <<= 1)
#pragma unroll
    for (int rs = 0; rs < 2; ++rs)
#pragma unroll
      for (int r = 0; r < 4; ++r) rsum[rs][r] += __shfl_xor(rsum[rs][r], msk, 64);
  if (ln == 0) {
#pragma unroll
    for (int rs = 0; rs < 2; ++rs)
#pragma unroll
      for (int r = 0; r < 4; ++r)
        atomicAdd(&rowsum_g[(size_t)b * SEQ + n0 + wv * 32 + rs * 16 + quad * 4 + r],
                  rsum[rs][r]);
  }
}

// ---------- attn: 64-n iterations (16 iters, 32 barriers/block vs R7's 64).
// Per iter: commit xg_l(64 rows) -> barrier -> E (2 slabs x 4 MFMA, 8 exp)
// -> barrier -> PV (16 MFMA, K=64). Math bit-identical to R7 (same per-slab
// MFMA order kk0h,kk0l,kk1h,kk1l; PV chunk0-then-chunk1 per accumulator).
// xv tiled [b][nt][c][32]; ri_l precomputed. U[half][b][m][c]; csum[half]. ----------
__global__ __launch_bounds__(512, 4) void attn_kernel(
    const u16* __restrict__ xg, const u16* __restrict__ xTh,
    const u16* __restrict__ xTl, const u16* __restrict__ xv,
    const float* __restrict__ rowsum_g,
    u16* __restrict__ U, float* __restrict__ csum) {
  __shared__ u16 xg_l[64 * 76];   // 9728 B (stride 38 dwords)
  __shared__ u16 p_l[64 * 72];    // [m][72], cols 0..63 used (stride 36 dwords)
  __shared__ float ri_l[1024];
  __shared__ float cs_l[64];
  const int tid = threadIdx.x;
  const int wv = tid >> 6, lane = tid & 63, quad = lane >> 4, ln = lane & 15;
  const int b = blockIdx.x & 7;
  const int m0 = ((blockIdx.x >> 3) & 31) << 6;
  const int half = blockIdx.x >> 8;
  const int nsub = wv & 1, msub = wv >> 1;

  if (tid < 64) cs_l[tid] = 0.f;
  {
    const float* rp = &rowsum_g[(size_t)b * SEQ + (half << 10)];
    ri_l[tid] = 1.0f / rp[tid];
    ri_l[tid + 512] = 1.0f / rp[tid + 512];
  }

  // persistent energy B-frags: keys m0 + msub*16 + ln, K=64, hi+lo
  bfrag8 bkh[2], bkl[2];
  {
    size_t base = ((size_t)b * SEQ + m0 + msub * 16 + ln) * NCK + quad * 8;
#pragma unroll
    for (int kk = 0; kk < 2; ++kk) {
      bkh[kk] = *(const bfrag8*)&xTh[base + kk * 32];
      bkl[kk] = *(const bfrag8*)&xTl[base + kk * 32];
    }
  }

  // prefetch state: xg slab (512 thr x 16B = 64 rows x 128B), xv frag pairs
  const int prow = tid >> 3, pcol = (tid & 7) << 3;
  const int t00 = half << 5;  // first 32n-tile index of this half
  uint4 pf0;
  bfrag8 avpf[2][2];          // [n-chunk][c-half]
  {
    pf0 = *(const uint4*)&xg[((size_t)b * SEQ + (t00 << 5) + prow) * NCK + pcol];
#pragma unroll
    for (int t = 0; t < 2; ++t) {
      const u16* vp = &xv[(((size_t)b * 64 + t00 + t) * NC + wv * 32 + ln) * 32 + quad * 8];
      avpf[t][0] = *(const bfrag8*)vp;
      avpf[t][1] = *(const bfrag8*)(vp + 512);
    }
  }

  ffrag4 acc[2][4];
#pragma unroll
  for (int ct = 0; ct < 2; ++ct)
#pragma unroll
    for (int s = 0; s < 4; ++s) acc[ct][s] = (ffrag4){0.f, 0.f, 0.f, 0.f};
  float cs = 0.f;

  for (int it = 0; it < 16; ++it) {
    // (a) commit prefetched data to LDS / regs
    bfrag8 av[2][2];
#pragma unroll
    for (int t = 0; t < 2; ++t) {
      av[t][0] = avpf[t][0];
      av[t][1] = avpf[t][1];
    }
    *(uint4*)&xg_l[prow * 76 + pcol] = pf0;
    // (b) issue next iteration's loads (clamped)
    {
      const int itn = (it + 1 < 16) ? it + 1 : it;
      pf0 = *(const uint4*)&xg[((size_t)b * SEQ + ((t00 + itn * 2) << 5) + prow) * NCK + pcol];
#pragma unroll
      for (int t = 0; t < 2; ++t) {
        const u16* vp =
            &xv[(((size_t)b * 64 + t00 + itn * 2 + t) * NC + wv * 32 + ln) * 32 + quad * 8];
        avpf[t][0] = *(const bfrag8*)vp;
        avpf[t][1] = *(const bfrag8*)(vp + 512);
      }
    }
    __syncthreads();
    // (d) E-phase: two 32-n slabs, each e in rowsum's order kk0h,kk0l,kk1h,kk1l
#pragma unroll
    for (int ns2 = 0; ns2 < 2; ++ns2) {
      ffrag4 e = {0.f, 0.f, 0.f, 0.f};
      const int arow = ns2 * 32 + nsub * 16 + ln;
      bfrag8 a0 = *(const bfrag8*)&xg_l[arow * 76 + quad * 8];
      bfrag8 a1 = *(const bfrag8*)&xg_l[arow * 76 + 32 + quad * 8];
      e = MFMA16(a0, bkh[0], e);
      e = MFMA16(a0, bkl[0], e);
      e = MFMA16(a1, bkh[1], e);
      e = MFMA16(a1, bkl[1], e);
      const float* rp = &ri_l[it * 64 + ns2 * 32 + nsub * 16 + quad * 4];
      float4 ri4 = *(const float4*)rp;
      float rr[4] = {ri4.x, ri4.y, ri4.z, ri4.w};
      u16 pu[4];
#pragma unroll
      for (int r = 0; r < 4; ++r) {
        float p = __expf(e[r]) * rr[r];
        cs += p;
        pu[r] = f2bf(p);
      }
      // p[m = msub*16+ln][n = ns2*32 + nsub*16 + quad*4 + r], row stride 72
      *(uint2*)&p_l[(msub * 16 + ln) * 72 + ns2 * 32 + nsub * 16 + quad * 4] =
          make_uint2((unsigned)pu[0] | ((unsigned)pu[1] << 16),
                     (unsigned)pu[2] | ((unsigned)pu[3] << 16));
    }
    __syncthreads();
    // (f) PV: K=64 = chunk0 then chunk1 per accumulator (same order as 2x R7 iters)
#pragma unroll
    for (int s = 0; s < 4; ++s) {
      bfrag8 pb0 = *(const bfrag8*)&p_l[(s * 16 + ln) * 72 + quad * 8];
      bfrag8 pb1 = *(const bfrag8*)&p_l[(s * 16 + ln) * 72 + 32 + quad * 8];
      acc[0][s] = MFMA16(av[0][0], pb0, acc[0][s]);
      acc[0][s] = MFMA16(av[1][0], pb1, acc[0][s]);
      acc[1][s] = MFMA16(av[0][1], pb0, acc[1][s]);
      acc[1][s] = MFMA16(av[1][1], pb1, acc[1][s]);
    }
  }

  cs += __shfl_down(cs, 32, 64);
  cs += __shfl_down(cs, 16, 64);
  if (lane < 16) atomicAdd(&cs_l[msub * 16 + ln], cs);
  __syncthreads();
  if (tid < 64) csum[((size_t)half * NB + b) * SEQ + m0 + tid] = cs_l[tid];

  // transposed epilogue: U[half][b][m][c], lane writes 4 consecutive c (uint2)
  u16* Uh = U + (size_t)half * NB * SEQ * NC;
#pragma unroll
  for (int ct = 0; ct < 2; ++ct)
#pragma unroll
    for (int s = 0; s < 4; ++s) {
      u16 pk[4];
#pragma unroll
      for (int r = 0; r < 4; ++r) pk[r] = f2bf(acc[ct][s][r]);
      *(uint2*)&Uh[((size_t)b * SEQ + m0 + s * 16 + ln) * NC + wv * 32 + ct * 16 + quad * 4] =
          make_uint2((unsigned)pk[0] | ((unsigned)pk[1] << 16),
                     (unsigned)pk[2] | ((unsigned)pk[3] << 16));
    }
}

// ---------- gemm_t: y[b][o][n] = Wt·x_r + bt with x_r = (U0+U1)·invcol fused in A-load.
// 2-pass hi/lo on W only; accumulates BN partial sums. ----------
__global__ __launch_bounds__(256, 2) void gemmt_kernel(
    const u16* __restrict__ U, const float* __restrict__ csum,
    const u16* __restrict__ Whi, const u16* __restrict__ Wlo,
    const float* __restrict__ bias, float* __restrict__ outp,
    float* __restrict__ ssum, float* __restrict__ sqsum) {
  constexpr int K = NC, SP = K + 8;
  __shared__ u16 lds[128 * SP];  // 67584 B (hi rows then lo rows)
  __shared__ float bsum[64], bsq[64];
  const int tid = threadIdx.x;
  const int wv = tid >> 6, lane = tid & 63, quad = lane >> 4, ln = lane & 15;
  const int b = blockIdx.x & 7, nt = blockIdx.x >> 3;
  const int o0 = blockIdx.y << 6, n0 = nt << 7;
  const size_t SZu = (size_t)NB * SEQ * NC;

  if (tid < 64) { bsum[tid] = 0.f; bsq[tid] = 0.f; }

  for (int i = tid; i < 64 * 32; i += 256) {
    int row = i >> 5, kc = (i & 31) * 8;
    *(uint4*)&lds[row * SP + kc] = *(const uint4*)&Whi[(size_t)(o0 + row) * K + kc];
    *(uint4*)&lds[(64 + row) * SP + kc] = *(const uint4*)&Wlo[(size_t)(o0 + row) * K + kc];
  }

  // A-frags: x_r rows = (U0+U1)*invcol, bf16
  bfrag8 af[2][8];
#pragma unroll
  for (int rs = 0; rs < 2; ++rs) {
    const int row = n0 + wv * 32 + rs * 16 + ln;
    const float ic = 1.0f / (1e-9f + csum[(size_t)b * SEQ + row] +
                             csum[((size_t)NB + b) * SEQ + row]);
    const u16* up = U + ((size_t)b * SEQ + row) * NC + quad * 8;
#pragma unroll
    for (int a = 0; a < 8; ++a) {
      bfrag8 u0 = *(const bfrag8*)(up + a * 32);
      bfrag8 u1 = *(const bfrag8*)(up + SZu + a * 32);
      union { u16 u[8]; bfrag8 f; } t;
#pragma unroll
      for (int j = 0; j < 8; ++j)
        t.u[j] = f2bf((bf2f((u16)u0[j]) + bf2f((u16)u1[j])) * ic);
      af[rs][a] = t.f;
    }
  }
  __syncthreads();

  ffrag4 acc[2][4];
#pragma unroll
  for (int ot = 0; ot < 4; ++ot) {
    ffrag4 e0 = {0.f, 0.f, 0.f, 0.f}, e1 = {0.f, 0.f, 0.f, 0.f};
#pragma unroll
    for (int a = 0; a < 8; ++a) {
      bfrag8 wh = *(const bfrag8*)&lds[(ot * 16 + ln) * SP + a * 32 + quad * 8];
      bfrag8 wl = *(const bfrag8*)&lds[(64 + ot * 16 + ln) * SP + a * 32 + quad * 8];
      e0 = MFMA16(wh, af[0][a], e0);
      e0 = MFMA16(wl, af[0][a], e0);
      e1 = MFMA16(wh, af[1][a], e1);
      e1 = MFMA16(wl, af[1][a], e1);
    }
    acc[0][ot] = e0;
    acc[1][ot] = e1;
  }
  __syncthreads();

  float* fl = (float*)lds;  // [64 o][132]
#pragma unroll
  for (int rs = 0; rs < 2; ++rs)
#pragma unroll
    for (int ot = 0; ot < 4; ++ot)
#pragma unroll
      for (int r = 0; r < 4; ++r)
        fl[(ot * 16 + quad * 4 + r) * 132 + wv * 32 + rs * 16 + ln] = acc[rs][ot][r];
  __syncthreads();
  for (int i = tid; i < 64 * 32; i += 256) {
    int row = i >> 5, n4 = (i & 31) * 4;
    float bb = (bias != nullptr) ? bias[o0 + row] : 0.f;
    const float* src = &fl[row * 132 + n4];
    float4 v = *(const float4*)src;
    v.x += bb; v.y += bb; v.z += bb; v.w += bb;
    *(float4*)&outp[((size_t)b * NC + o0 + row) * SEQ + n0 + n4] = v;
    float s = v.x + v.y + v.z + v.w;
    float sq = v.x * v.x + v.y * v.y + v.z * v.z + v.w * v.w;
    atomicAdd(&bsum[row], s);
    atomicAdd(&bsq[row], sq);
  }
  __syncthreads();
  if (tid < 64) {
    atomicAdd(&ssum[o0 + tid], bsum[tid]);
    atomicAdd(&sqsum[o0 + tid], bsq[tid]);
  }
}

// ---------- BN normalize + ReLU ----------
__global__ __launch_bounds__(256) void bnorm_kernel(
    const float* __restrict__ y, const float* __restrict__ ssum, const float* __restrict__ sqsum,
    const float* __restrict__ gamma, const float* __restrict__ beta, float* __restrict__ out) {
  size_t e0 = ((size_t)blockIdx.x * 256 + threadIdx.x) * 4;
  int o = (int)((e0 >> 11) & (NC - 1));
  const float invn = 1.0f / 16384.0f;
  float mean = ssum[o] * invn;
  float var = sqsum[o] * invn - mean * mean;
  float rs = rsqrtf(var + 1e-5f);
  float a = gamma[o] * rs;
  float c = beta[o] - mean * a;
  float4 v = *(const float4*)(y + e0);
  float4 r;
  r.x = fmaxf(0.f, fmaf(v.x, a, c));
  r.y = fmaxf(0.f, fmaf(v.y, a, c));
  r.z = fmaxf(0.f, fmaf(v.z, a, c));
  r.w = fmaxf(0.f, fmaf(v.w, a, c));
  *(float4*)(out + e0) = r;
}

extern "C" void kernel_launch(void* const* d_in, const int* in_sizes, int n_in,
                              void* d_out, int out_size, void* d_ws, size_t ws_size,
                              hipStream_t stream) {
  const float* q     = (const float*)d_in[0];
  const float* x     = (const float*)d_in[1];
  const float* Wq    = (const float*)d_in[2];
  const float* Wk    = (const float*)d_in[3];
  const float* Wv    = (const float*)d_in[4];
  const float* bv    = (const float*)d_in[5];
  const float* Wt    = (const float*)d_in[6];
  const float* bt    = (const float*)d_in[7];
  const float* gamma = (const float*)d_in[8];
  const float* beta  = (const float*)d_in[9];
  float* out = (float*)d_out;

  // Arena (phase-overlaid). SZ = 4,194,304 elems; SZB = 16 MB. ws >= 128 MiB (verified R2).
  // [0,16M):  qT hi/lo       -> later U half0 [B][M][C]
  // [0,32M):  U [2][B][M][C] bf16 (after projections; qT dead)
  // [32,48M): y fp32 [B][C][N] (gemmt output)
  // [48,56M): xv bf16 TILED [B][64 nt][C][32 n]
  // [56M+):   wpack (Wv/Wt hi/lo), rowsum_g, csum[2], ssum/sqsum
  // [64M,66M): xT_hi [B][N][64]   [66M,68M): xT_lo
  // [72M,74M): xg [B][N][64] bf16
  // [78M+):    G' hi/lo [64][256]
  const size_t SZ = (size_t)NB * NC * SEQ;
  const size_t SZB = SZ * 4;
  char* wsb = (char*)d_ws;
  u16* qT_hi = (u16*)(wsb);
  u16* qT_lo = qT_hi + SZ;
  u16* Ua    = (u16*)(wsb);                 // [2][B][SEQ][NC]
  float* y   = (float*)(wsb + 2 * SZB);
  u16* xv    = (u16*)(wsb + 3 * SZB);
  u16* wpack = (u16*)(wsb + 3 * SZB + SZB / 2);
  u16* Wv_hi = wpack + 131072, *Wv_lo = wpack + 196608;
  u16* Wt_hi = wpack + 262144, *Wt_lo = wpack + 327680;
  float* rowsum_g = (float*)(wpack + 425984);     // [B][SEQ]
  float* csum = rowsum_g + (size_t)NB * SEQ;      // [2][B][SEQ]
  float* ssum = csum + 2 * (size_t)NB * SEQ;      // [256]
  float* sqsum = ssum + NC;                       // [256]
  u16* xT_hi = (u16*)(wsb + ((size_t)64 << 20));
  u16* xT_lo = (u16*)(wsb + ((size_t)66 << 20));
  u16* xg    = (u16*)(wsb + ((size_t)72 << 20));
  u16* Gp_hi = (u16*)(wsb + ((size_t)78 << 20));
  u16* Gp_lo = Gp_hi + 64 * 256;

  wconv_kernel<<<577, 256, 0, stream>>>(Wv, Wt, wpack, ssum, rowsum_g);
  tconv_kernel<NC><<<dim3(64, 64), 256, 0, stream>>>(q, qT_hi, qT_lo);
  tconv_kernel<NCK><<<dim3(16, 64), 256, 0, stream>>>(x, xT_hi, xT_lo);
  gcomp_kernel<<<64, 256, 0, stream>>>(Wq, Wk, Gp_hi, Gp_lo);

  const size_t shm256 = 64 * (256 + 8) * 2 * sizeof(u16);  // 67,584 B
  gemm_kernel<256><<<dim3(128, 4), 256, shm256, stream>>>(
      qT_hi, qT_lo, Wv_hi, Wv_lo, bv, xv);
  gemmxg_kernel<<<128, 256, 0, stream>>>(qT_hi, qT_lo, Gp_hi, Gp_lo, xg);

  rowsum_kernel<<<512, 256, 0, stream>>>(xg, xT_hi, xT_lo, rowsum_g);
  attn_kernel<<<512, 512, 0, stream>>>(xg, xT_hi, xT_lo, xv, rowsum_g, Ua, csum);
  gemmt_kernel<<<dim3(128, 4), 256, 0, stream>>>(
      Ua, csum, Wt_hi, Wt_lo, bt, y, ssum, sqsum);

  bnorm_kernel<<<4096, 256, 0, stream>>>(y, ssum, sqsum, gamma, beta, out);
}

// Round 9
// 207.192 us; speedup vs baseline: 1.0359x; 1.0359x over previous
//
#include <hip/hip_runtime.h>
#include <hip/hip_bf16.h>

#define NB  8
#define NC  256
#define NCK 64
#define SEQ 2048

typedef unsigned short u16;
typedef short bfrag8 __attribute__((ext_vector_type(8)));   // 8 bf16 (4 VGPRs)
typedef float ffrag4 __attribute__((ext_vector_type(4)));   // 4 fp32 acc

#define MFMA16(a, b, c) __builtin_amdgcn_mfma_f32_16x16x32_bf16((a), (b), (c), 0, 0, 0)

static __device__ __forceinline__ u16 f2bf(float f) {
  return __builtin_bit_cast(u16, (__bf16)f);  // RNE
}
static __device__ __forceinline__ float bf2f(u16 u) {
  unsigned v = (unsigned)u << 16;
  return __builtin_bit_cast(float, v);
}

// ---------- W fp32 -> bf16 hi/lo for Wv, Wt; tail blocks: zero ssum/sqsum+rowsum_g,
// and G' = Wk^T*Wq (blocks 577..640, one ck row each) ----------
__global__ __launch_bounds__(256) void wconv_kernel(
    const float* __restrict__ Wv, const float* __restrict__ Wt,
    u16* __restrict__ dst, float* __restrict__ zz, float* __restrict__ rowsum_g,
    const float* __restrict__ Wq, const float* __restrict__ Wk,
    u16* __restrict__ Gh, u16* __restrict__ Gl) {
  int bx = blockIdx.x;
  if (bx >= 512) {
    if (bx == 512) {
      zz[threadIdx.x] = 0.f;
      zz[256 + threadIdx.x] = 0.f;
    } else if (bx < 577) {
      rowsum_g[(bx - 513) * 256 + threadIdx.x] = 0.f;
    } else {
      // gcomp: G'[ck][c] = sum_o Wq[o][c]*Wk[o][ck]
      const int ck = bx - 577, c = threadIdx.x;
      float s = 0.f;
#pragma unroll 8
      for (int o = 0; o < 256; ++o) s += Wq[o * 256 + c] * Wk[o * 64 + ck];
      u16 h = f2bf(s);
      Gh[ck * 256 + c] = h;
      Gl[ck * 256 + c] = f2bf(s - bf2f(h));
    }
    return;
  }
  int id = bx * 256 + threadIdx.x;
  const float* src;
  int off;
  if (id < 65536) { src = Wv; off = 131072; }
  else            { src = Wt; off = 262144; id -= 65536; }
  float v = src[id];
  u16 h = f2bf(v);
  u16 l = f2bf(v - bf2f(h));
  dst[off + id] = h;
  dst[off + 65536 + id] = l;
}

// ---------- transpose-convert body: in fp32 [b][CIN][n] -> Thi/Tlo bf16 [b][n][CIN] ----------
template <int CIN>
static __device__ __forceinline__ void tconv_body(
    const float* __restrict__ in, u16* __restrict__ Thi, u16* __restrict__ Tlo,
    int bxl, int by, int tid) {
  __shared__ float t[32][33];
  const int b = bxl & 7, cg = bxl >> 3;
  const int c0 = cg << 5, n0 = by << 5;
  {
    int c = tid >> 3, m4 = (tid & 7) << 2;
    float4 v = *(const float4*)&in[((size_t)b * CIN + c0 + c) * SEQ + n0 + m4];
    t[c][m4 + 0] = v.x; t[c][m4 + 1] = v.y; t[c][m4 + 2] = v.z; t[c][m4 + 3] = v.w;
  }
  __syncthreads();
  {
    int n = tid >> 3, c4 = (tid & 7) << 2;
    u16 h[4], l[4];
#pragma unroll
    for (int j = 0; j < 4; ++j) {
      float v = t[c4 + j][n];
      h[j] = f2bf(v);
      l[j] = f2bf(v - bf2f(h[j]));
    }
    size_t base = ((size_t)b * SEQ + n0 + n) * CIN + c0 + c4;
    *(uint2*)&Thi[base] = make_uint2((unsigned)h[0] | ((unsigned)h[1] << 16),
                                     (unsigned)h[2] | ((unsigned)h[3] << 16));
    *(uint2*)&Tlo[base] = make_uint2((unsigned)l[0] | ((unsigned)l[1] << 16),
                                     (unsigned)l[2] | ((unsigned)l[3] << 16));
  }
}

// merged launch: bx<64 -> q (CIN=256); bx>=64 -> x (CIN=64)
__global__ __launch_bounds__(256) void tconv2_kernel(
    const float* __restrict__ q, const float* __restrict__ x,
    u16* __restrict__ qTh, u16* __restrict__ qTl,
    u16* __restrict__ xTh, u16* __restrict__ xTl) {
  if (blockIdx.x < 64)
    tconv_body<NC>(q, qTh, qTl, blockIdx.x, blockIdx.y, threadIdx.x);
  else
    tconv_body<NCK>(x, xTh, xTl, blockIdx.x - 64, blockIdx.y, threadIdx.x);
}

// ---------- MFMA GEMM hi/lo split (3-pass): x_v projection, out bf16 tiled
// xv_t[b][nt=n/32][o][32n] (+bias) for coalesced PV loads in attn ----------
template <int K>
__global__ __launch_bounds__(256, 2) void gemm_kernel(
    const u16* __restrict__ Ahi, const u16* __restrict__ Alo,
    const u16* __restrict__ Whi, const u16* __restrict__ Wlo,
    const float* __restrict__ bias, u16* __restrict__ outp) {
  constexpr int SP = K + 8;
  extern __shared__ u16 lds[];  // 64*SP*2 shorts (hi rows then lo rows)
  const int tid = threadIdx.x;
  const int wv = tid >> 6, lane = tid & 63, quad = lane >> 4, ln = lane & 15;
  const int b = blockIdx.x & 7, nt = blockIdx.x >> 3;
  const int o0 = blockIdx.y << 6, n0 = nt << 7;

  constexpr int RW = K / 8;
  for (int i = tid; i < 64 * RW; i += 256) {
    int row = i / RW, kc = (i % RW) * 8;
    *(uint4*)&lds[row * SP + kc] = *(const uint4*)&Whi[(size_t)(o0 + row) * K + kc];
    *(uint4*)&lds[(64 + row) * SP + kc] = *(const uint4*)&Wlo[(size_t)(o0 + row) * K + kc];
  }
  constexpr int NA = K / 32;
  bfrag8 ahi[2][NA], alo[2][NA];
#pragma unroll
  for (int rs = 0; rs < 2; ++rs) {
    const u16* ap = Ahi + ((size_t)b * SEQ + n0 + wv * 32 + rs * 16 + ln) * K + quad * 8;
    const u16* al = Alo + ((size_t)b * SEQ + n0 + wv * 32 + rs * 16 + ln) * K + quad * 8;
#pragma unroll
    for (int a = 0; a < NA; ++a) {
      ahi[rs][a] = *(const bfrag8*)(ap + a * 32);
      alo[rs][a] = *(const bfrag8*)(al + a * 32);
    }
  }
  __syncthreads();

  ffrag4 acc[2][4];
#pragma unroll
  for (int ot = 0; ot < 4; ++ot) {
    ffrag4 e0 = {0.f, 0.f, 0.f, 0.f}, e1 = {0.f, 0.f, 0.f, 0.f};
#pragma unroll
    for (int a = 0; a < NA; ++a) {
      bfrag8 wh = *(const bfrag8*)&lds[(ot * 16 + ln) * SP + a * 32 + quad * 8];
      bfrag8 wl = *(const bfrag8*)&lds[(64 + ot * 16 + ln) * SP + a * 32 + quad * 8];
      e0 = MFMA16(wh, ahi[0][a], e0);
      e0 = MFMA16(wh, alo[0][a], e0);
      e0 = MFMA16(wl, ahi[0][a], e0);
      e1 = MFMA16(wh, ahi[1][a], e1);
      e1 = MFMA16(wh, alo[1][a], e1);
      e1 = MFMA16(wl, ahi[1][a], e1);
    }
    acc[0][ot] = e0;
    acc[1][ot] = e1;
  }
  __syncthreads();  // lds free for epilogue

  u16* tl = lds;  // [64 o][136]
#pragma unroll
  for (int rs = 0; rs < 2; ++rs)
#pragma unroll
    for (int ot = 0; ot < 4; ++ot)
#pragma unroll
      for (int r = 0; r < 4; ++r)
        tl[(ot * 16 + quad * 4 + r) * 136 + wv * 32 + rs * 16 + ln] = f2bf(acc[rs][ot][r]);
  __syncthreads();
  for (int i = tid; i < 64 * 16; i += 256) {
    int row = i >> 4, n8 = (i & 15) * 8;
    float bb = (bias != nullptr) ? bias[o0 + row] : 0.f;
    u16 pk[8];
#pragma unroll
    for (int j = 0; j < 8; ++j) pk[j] = f2bf(bf2f(tl[row * 136 + n8 + j]) + bb);
    int t = (n0 + n8) >> 5, no = n8 & 31;
    *(uint4*)&outp[(((size_t)b * 64 + t) * NC + o0 + row) * 32 + no] = *(uint4*)pk;
  }
}

// ---------- gemmxg: xg[b][n][64] = qT(hi/lo) x G'(hi/lo), 3-pass, bf16-hi out ----------
__global__ __launch_bounds__(256, 2) void gemmxg_kernel(
    const u16* __restrict__ Ahi, const u16* __restrict__ Alo,
    const u16* __restrict__ Gh, const u16* __restrict__ Gl,
    u16* __restrict__ xg) {
  constexpr int K = 256, SP = K + 8;
  __shared__ u16 lds[128 * SP];  // 67584 B: G' hi rows 0..63, lo rows 64..127
  const int tid = threadIdx.x;
  const int wv = tid >> 6, lane = tid & 63, quad = lane >> 4, ln = lane & 15;
  const int b = blockIdx.x & 7, nt = blockIdx.x >> 3;
  const int n0 = nt << 7;

  for (int i = tid; i < 64 * 32; i += 256) {
    int row = i >> 5, kc = (i & 31) * 8;
    *(uint4*)&lds[row * SP + kc] = *(const uint4*)&Gh[(size_t)row * K + kc];
    *(uint4*)&lds[(64 + row) * SP + kc] = *(const uint4*)&Gl[(size_t)row * K + kc];
  }
  bfrag8 ahi[2][8], alo[2][8];
#pragma unroll
  for (int rs = 0; rs < 2; ++rs) {
    const u16* ap = Ahi + ((size_t)b * SEQ + n0 + wv * 32 + rs * 16 + ln) * K + quad * 8;
    const u16* al = Alo + ((size_t)b * SEQ + n0 + wv * 32 + rs * 16 + ln) * K + quad * 8;
#pragma unroll
    for (int a = 0; a < 8; ++a) {
      ahi[rs][a] = *(const bfrag8*)(ap + a * 32);
      alo[rs][a] = *(const bfrag8*)(al + a * 32);
    }
  }
  __syncthreads();

  ffrag4 acc[2][4];
#pragma unroll
  for (int ot = 0; ot < 4; ++ot) {
    ffrag4 e0 = {0.f, 0.f, 0.f, 0.f}, e1 = {0.f, 0.f, 0.f, 0.f};
#pragma unroll
    for (int a = 0; a < 8; ++a) {
      bfrag8 wh = *(const bfrag8*)&lds[(ot * 16 + ln) * SP + a * 32 + quad * 8];
      bfrag8 wl = *(const bfrag8*)&lds[(64 + ot * 16 + ln) * SP + a * 32 + quad * 8];
      e0 = MFMA16(ahi[0][a], wh, e0);
      e0 = MFMA16(alo[0][a], wh, e0);
      e0 = MFMA16(ahi[0][a], wl, e0);
      e1 = MFMA16(ahi[1][a], wh, e1);
      e1 = MFMA16(alo[1][a], wh, e1);
      e1 = MFMA16(ahi[1][a], wl, e1);
    }
    acc[0][ot] = e0;
    acc[1][ot] = e1;
  }
  __syncthreads();

  u16* tl = lds;  // [128 n][72], cols 0..63 used
#pragma unroll
  for (int rs = 0; rs < 2; ++rs)
#pragma unroll
    for (int ot = 0; ot < 4; ++ot)
#pragma unroll
      for (int r = 0; r < 4; ++r)
        tl[(wv * 32 + rs * 16 + quad * 4 + r) * 72 + ot * 16 + ln] = f2bf(acc[rs][ot][r]);
  __syncthreads();
  for (int i = tid; i < 128 * 8; i += 256) {
    int row = i >> 3, c8 = (i & 7) * 8;
    *(uint4*)&xg[((size_t)b * SEQ + n0 + row) * NCK + c8] = *(uint4*)&tl[row * 72 + c8];
  }
}

// ---------- rowsum: rowsum_g[b,n] += sum_m exp(e[n,m]), K=64 energy, 2-pass xT hi/lo.
// LDS-staged, double-buffered (R3 structure). ----------
__global__ __launch_bounds__(256, 2) void rowsum_kernel(
    const u16* __restrict__ xg, const u16* __restrict__ xTh,
    const u16* __restrict__ xTl, float* __restrict__ rowsum_g) {
  __shared__ u16 bk_l[2][2][64 * 76];  // [dbuf][hi/lo], 4 x 9728 B
  const int tid = threadIdx.x;
  const int wv = tid >> 6, lane = tid & 63, quad = lane >> 4, ln = lane & 15;
  const int b  = blockIdx.x & 7;
  const int nt = (blockIdx.x >> 3) & 15;
  const int mh = blockIdx.x >> 7;   // 0..3
  const int n0 = nt << 7;
  const int m0 = mh << 9;

  bfrag8 aq[2][2];
#pragma unroll
  for (int rs = 0; rs < 2; ++rs) {
    const u16* qp = xg + ((size_t)b * SEQ + n0 + wv * 32 + rs * 16 + ln) * NCK + quad * 8;
    aq[rs][0] = *(const bfrag8*)qp;
    aq[rs][1] = *(const bfrag8*)(qp + 32);
  }

  const int srow = tid >> 2, scol = (tid & 3) << 4;
  uint4 ph0, ph1, pl0, pl1;
  {
    size_t base = ((size_t)b * SEQ + m0 + srow) * NCK + scol;
    ph0 = *(const uint4*)&xTh[base];     ph1 = *(const uint4*)&xTh[base + 8];
    pl0 = *(const uint4*)&xTl[base];     pl1 = *(const uint4*)&xTl[base + 8];
  }

  float rsum[2][4];
#pragma unroll
  for (int rs = 0; rs < 2; ++rs)
#pragma unroll
    for (int r = 0; r < 4; ++r) rsum[rs][r] = 0.f;

  for (int ch = 0; ch < 8; ++ch) {
    u16* bh = &bk_l[ch & 1][0][srow * 76 + scol];
    u16* bl = &bk_l[ch & 1][1][srow * 76 + scol];
    *(uint4*)bh = ph0; *(uint4*)(bh + 8) = ph1;
    *(uint4*)bl = pl0; *(uint4*)(bl + 8) = pl1;
    if (ch < 7) {
      size_t base = ((size_t)b * SEQ + m0 + (ch + 1) * 64 + srow) * NCK + scol;
      ph0 = *(const uint4*)&xTh[base];   ph1 = *(const uint4*)&xTh[base + 8];
      pl0 = *(const uint4*)&xTl[base];   pl1 = *(const uint4*)&xTl[base + 8];
    }
    __syncthreads();

    ffrag4 e[2][4];
#pragma unroll
    for (int rs = 0; rs < 2; ++rs)
#pragma unroll
      for (int ms = 0; ms < 4; ++ms) e[rs][ms] = (ffrag4){0.f, 0.f, 0.f, 0.f};
#pragma unroll
    for (int ms = 0; ms < 4; ++ms)
#pragma unroll
      for (int kk = 0; kk < 2; ++kk) {
        bfrag8 bbh = *(const bfrag8*)&bk_l[ch & 1][0][(ms * 16 + ln) * 76 + kk * 32 + quad * 8];
        bfrag8 bbl = *(const bfrag8*)&bk_l[ch & 1][1][(ms * 16 + ln) * 76 + kk * 32 + quad * 8];
        // op order per accumulator must match attn_kernel exactly: kk0h,kk0l,kk1h,kk1l
        e[0][ms] = MFMA16(aq[0][kk], bbh, e[0][ms]);
        e[0][ms] = MFMA16(aq[0][kk], bbl, e[0][ms]);
        e[1][ms] = MFMA16(aq[1][kk], bbh, e[1][ms]);
        e[1][ms] = MFMA16(aq[1][kk], bbl, e[1][ms]);
      }
#pragma unroll
    for (int rs = 0; rs < 2; ++rs)
#pragma unroll
      for (int ms = 0; ms < 4; ++ms)
#pragma unroll
        for (int r = 0; r < 4; ++r) rsum[rs][r] += __expf(e[rs][ms][r]);
  }

#pragma unroll
  for (int msk = 1; msk < 16; msk <<= 1)
#pragma unroll
    for (int rs = 0; rs < 2; ++rs)
#pragma unroll
      for (int r = 0; r < 4; ++r) rsum[rs][r] += __shfl_xor(rsum[rs][r], msk, 64);
  if (ln == 0) {
#pragma unroll
    for (int rs = 0; rs < 2; ++rs)
#pragma unroll
      for (int r = 0; r < 4; ++r)
        atomicAdd(&rowsum_g[(size_t)b * SEQ + n0 + wv * 32 + rs * 16 + quad * 4 + r],
                  rsum[rs][r]);
  }
}

// ---------- attn: exact R7 structure (2 barriers/iter, LDS-staged xg, single p_l),
// ri_l[1024] precomputed once, xv tiled [b][nt][c][32] for coalesced PV loads.
// U[half][b][m][c] bf16; csum[half][b][m] partials. ----------
__global__ __launch_bounds__(512, 4) void attn_kernel(
    const u16* __restrict__ xg, const u16* __restrict__ xTh,
    const u16* __restrict__ xTl, const u16* __restrict__ xv,
    const float* __restrict__ rowsum_g,
    u16* __restrict__ U, float* __restrict__ csum) {
  __shared__ u16 xg_l[32 * 76];   // 4864 B, conflict-free (stride 38 dwords)
  __shared__ u16 p_l[64 * 40];    // [row m][40], cols 0..31 used
  __shared__ float ri_l[1024];
  __shared__ float cs_l[64];
  const int tid = threadIdx.x;
  const int wv = tid >> 6, lane = tid & 63, quad = lane >> 4, ln = lane & 15;
  const int b = blockIdx.x & 7;
  const int m0 = ((blockIdx.x >> 3) & 31) << 6;
  const int half = blockIdx.x >> 8;
  const int nsub = wv & 1, msub = wv >> 1;
  const int nt0 = half * 32, ntEnd = nt0 + 32;

  if (tid < 64) cs_l[tid] = 0.f;
  {
    const float* rp = &rowsum_g[(size_t)b * SEQ + (half << 10)];
    ri_l[tid] = 1.0f / rp[tid];
    ri_l[tid + 512] = 1.0f / rp[tid + 512];
  }

  // persistent energy B-frags: keys m0 + msub*16 + ln, K=64, hi+lo
  bfrag8 bkh[2], bkl[2];
  {
    size_t base = ((size_t)b * SEQ + m0 + msub * 16 + ln) * NCK + quad * 8;
#pragma unroll
    for (int kk = 0; kk < 2; ++kk) {
      bkh[kk] = *(const bfrag8*)&xTh[base + kk * 32];
      bkl[kk] = *(const bfrag8*)&xTl[base + kk * 32];
    }
  }

  // prefetch state: xg tile (tid<256: 16B/thread), this wave's xv frags (tiled)
  const int prow = (tid & 255) >> 3, pcol = (tid & 7) << 3;
  uint4 pf0 = {0, 0, 0, 0};
  bfrag8 avpf0, avpf1;
  {
    if (tid < 256)
      pf0 = *(const uint4*)&xg[((size_t)b * SEQ + (nt0 << 5) + prow) * NCK + pcol];
    const u16* vp = &xv[(((size_t)b * 64 + nt0) * NC + wv * 32 + ln) * 32 + quad * 8];
    avpf0 = *(const bfrag8*)vp;
    avpf1 = *(const bfrag8*)(vp + 512);   // c + 16 rows
  }

  ffrag4 acc[2][4];
#pragma unroll
  for (int ct = 0; ct < 2; ++ct)
#pragma unroll
    for (int s = 0; s < 4; ++s) acc[ct][s] = (ffrag4){0.f, 0.f, 0.f, 0.f};
  float cs = 0.f;

  for (int nt = nt0; nt < ntEnd; ++nt) {
    // (a) commit prefetched data to LDS / regs
    bfrag8 av0 = avpf0, av1 = avpf1;
    if (tid < 256) *(uint4*)&xg_l[prow * 76 + pcol] = pf0;
    // (b) issue next iteration's loads
    {
      const int ntn = (nt + 1 < ntEnd) ? nt + 1 : nt;
      if (tid < 256)
        pf0 = *(const uint4*)&xg[((size_t)b * SEQ + (ntn << 5) + prow) * NCK + pcol];
      const u16* vp = &xv[(((size_t)b * 64 + ntn) * NC + wv * 32 + ln) * 32 + quad * 8];
      avpf0 = *(const bfrag8*)vp;
      avpf1 = *(const bfrag8*)(vp + 512);
    }
    __syncthreads();
    // (d) E-phase: e = sum_kk [ xg_hi*xT_hi + xg_hi*xT_lo ]
    {
      ffrag4 e = {0.f, 0.f, 0.f, 0.f};
#pragma unroll
      for (int kk = 0; kk < 2; ++kk) {
        bfrag8 a = *(const bfrag8*)&xg_l[(nsub * 16 + ln) * 76 + kk * 32 + quad * 8];
        e = MFMA16(a, bkh[kk], e);
        e = MFMA16(a, bkl[kk], e);
      }
      const float* rp = &ri_l[((nt - nt0) << 5) + nsub * 16 + quad * 4];
      float4 ri4 = *(const float4*)rp;
      float rr[4] = {ri4.x, ri4.y, ri4.z, ri4.w};
      u16 pu[4];
#pragma unroll
      for (int r = 0; r < 4; ++r) {
        float p = __expf(e[r]) * rr[r];
        cs += p;
        pu[r] = f2bf(p);
      }
      // p[m = msub*16+ln][n = nsub*16 + quad*4 + r], row stride 40
      *(uint2*)&p_l[(msub * 16 + ln) * 40 + nsub * 16 + quad * 4] =
          make_uint2((unsigned)pu[0] | ((unsigned)pu[1] << 16),
                     (unsigned)pu[2] | ((unsigned)pu[3] << 16));
    }
    __syncthreads();
    // (f) PV: 16B read = n-chunk quad*8 of row (s*16+ln)
#pragma unroll
    for (int s = 0; s < 4; ++s) {
      bfrag8 pb = *(const bfrag8*)&p_l[(s * 16 + ln) * 40 + quad * 8];
      acc[0][s] = MFMA16(av0, pb, acc[0][s]);
      acc[1][s] = MFMA16(av1, pb, acc[1][s]);
    }
  }

  cs += __shfl_down(cs, 32, 64);
  cs += __shfl_down(cs, 16, 64);
  if (lane < 16) atomicAdd(&cs_l[msub * 16 + ln], cs);
  __syncthreads();
  if (tid < 64) csum[((size_t)half * NB + b) * SEQ + m0 + tid] = cs_l[tid];

  // transposed epilogue: U[half][b][m][c], lane writes 4 consecutive c (uint2)
  u16* Uh = U + (size_t)half * NB * SEQ * NC;
#pragma unroll
  for (int ct = 0; ct < 2; ++ct)
#pragma unroll
    for (int s = 0; s < 4; ++s) {
      u16 pk[4];
#pragma unroll
      for (int r = 0; r < 4; ++r) pk[r] = f2bf(acc[ct][s][r]);
      *(uint2*)&Uh[((size_t)b * SEQ + m0 + s * 16 + ln) * NC + wv * 32 + ct * 16 + quad * 4] =
          make_uint2((unsigned)pk[0] | ((unsigned)pk[1] << 16),
                     (unsigned)pk[2] | ((unsigned)pk[3] << 16));
    }
}

// ---------- gemm_t: y[b][o][n] = Wt·x_r + bt with x_r = (U0+U1)·invcol fused in A-load.
// 2-pass hi/lo on W only; accumulates BN partial sums. ----------
__global__ __launch_bounds__(256, 2) void gemmt_kernel(
    const u16* __restrict__ U, const float* __restrict__ csum,
    const u16* __restrict__ Whi, const u16* __restrict__ Wlo,
    const float* __restrict__ bias, float* __restrict__ outp,
    float* __restrict__ ssum, float* __restrict__ sqsum) {
  constexpr int K = NC, SP = K + 8;
  __shared__ u16 lds[128 * SP];  // 67584 B (hi rows then lo rows)
  __shared__ float bsum[64], bsq[64];
  const int tid = threadIdx.x;
  const int wv = tid >> 6, lane = tid & 63, quad = lane >> 4, ln = lane & 15;
  const int b = blockIdx.x & 7, nt = blockIdx.x >> 3;
  const int o0 = blockIdx.y << 6, n0 = nt << 7;
  const size_t SZu = (size_t)NB * SEQ * NC;

  if (tid < 64) { bsum[tid] = 0.f; bsq[tid] = 0.f; }

  for (int i = tid; i < 64 * 32; i += 256) {
    int row = i >> 5, kc = (i & 31) * 8;
    *(uint4*)&lds[row * SP + kc] = *(const uint4*)&Whi[(size_t)(o0 + row) * K + kc];
    *(uint4*)&lds[(64 + row) * SP + kc] = *(const uint4*)&Wlo[(size_t)(o0 + row) * K + kc];
  }

  // A-frags: x_r rows = (U0+U1)*invcol, bf16
  bfrag8 af[2][8];
#pragma unroll
  for (int rs = 0; rs < 2; ++rs) {
    const int row = n0 + wv * 32 + rs * 16 + ln;
    const float ic = 1.0f / (1e-9f + csum[(size_t)b * SEQ + row] +
                             csum[((size_t)NB + b) * SEQ + row]);
    const u16* up = U + ((size_t)b * SEQ + row) * NC + quad * 8;
#pragma unroll
    for (int a = 0; a < 8; ++a) {
      bfrag8 u0 = *(const bfrag8*)(up + a * 32);
      bfrag8 u1 = *(const bfrag8*)(up + SZu + a * 32);
      union { u16 u[8]; bfrag8 f; } t;
#pragma unroll
      for (int j = 0; j < 8; ++j)
        t.u[j] = f2bf((bf2f((u16)u0[j]) + bf2f((u16)u1[j])) * ic);
      af[rs][a] = t.f;
    }
  }
  __syncthreads();

  ffrag4 acc[2][4];
#pragma unroll
  for (int ot = 0; ot < 4; ++ot) {
    ffrag4 e0 = {0.f, 0.f, 0.f, 0.f}, e1 = {0.f, 0.f, 0.f, 0.f};
#pragma unroll
    for (int a = 0; a < 8; ++a) {
      bfrag8 wh = *(const bfrag8*)&lds[(ot * 16 + ln) * SP + a * 32 + quad * 8];
      bfrag8 wl = *(const bfrag8*)&lds[(64 + ot * 16 + ln) * SP + a * 32 + quad * 8];
      e0 = MFMA16(wh, af[0][a], e0);
      e0 = MFMA16(wl, af[0][a], e0);
      e1 = MFMA16(wh, af[1][a], e1);
      e1 = MFMA16(wl, af[1][a], e1);
    }
    acc[0][ot] = e0;
    acc[1][ot] = e1;
  }
  __syncthreads();

  float* fl = (float*)lds;  // [64 o][132]
#pragma unroll
  for (int rs = 0; rs < 2; ++rs)
#pragma unroll
    for (int ot = 0; ot < 4; ++ot)
#pragma unroll
      for (int r = 0; r < 4; ++r)
        fl[(ot * 16 + quad * 4 + r) * 132 + wv * 32 + rs * 16 + ln] = acc[rs][ot][r];
  __syncthreads();
  for (int i = tid; i < 64 * 32; i += 256) {
    int row = i >> 5, n4 = (i & 31) * 4;
    float bb = (bias != nullptr) ? bias[o0 + row] : 0.f;
    const float* src = &fl[row * 132 + n4];
    float4 v = *(const float4*)src;
    v.x += bb; v.y += bb; v.z += bb; v.w += bb;
    *(float4*)&outp[((size_t)b * NC + o0 + row) * SEQ + n0 + n4] = v;
    float s = v.x + v.y + v.z + v.w;
    float sq = v.x * v.x + v.y * v.y + v.z * v.z + v.w * v.w;
    atomicAdd(&bsum[row], s);
    atomicAdd(&bsq[row], sq);
  }
  __syncthreads();
  if (tid < 64) {
    atomicAdd(&ssum[o0 + tid], bsum[tid]);
    atomicAdd(&sqsum[o0 + tid], bsq[tid]);
  }
}

// ---------- BN normalize + ReLU ----------
__global__ __launch_bounds__(256) void bnorm_kernel(
    const float* __restrict__ y, const float* __restrict__ ssum, const float* __restrict__ sqsum,
    const float* __restrict__ gamma, const float* __restrict__ beta, float* __restrict__ out) {
  size_t e0 = ((size_t)blockIdx.x * 256 + threadIdx.x) * 4;
  int o = (int)((e0 >> 11) & (NC - 1));
  const float invn = 1.0f / 16384.0f;
  float mean = ssum[o] * invn;
  float var = sqsum[o] * invn - mean * mean;
  float rs = rsqrtf(var + 1e-5f);
  float a = gamma[o] * rs;
  float c = beta[o] - mean * a;
  float4 v = *(const float4*)(y + e0);
  float4 r;
  r.x = fmaxf(0.f, fmaf(v.x, a, c));
  r.y = fmaxf(0.f, fmaf(v.y, a, c));
  r.z = fmaxf(0.f, fmaf(v.z, a, c));
  r.w = fmaxf(0.f, fmaf(v.w, a, c));
  *(float4*)(out + e0) = r;
}

extern "C" void kernel_launch(void* const* d_in, const int* in_sizes, int n_in,
                              void* d_out, int out_size, void* d_ws, size_t ws_size,
                              hipStream_t stream) {
  const float* q     = (const float*)d_in[0];
  const float* x     = (const float*)d_in[1];
  const float* Wq    = (const float*)d_in[2];
  const float* Wk    = (const float*)d_in[3];
  const float* Wv    = (const float*)d_in[4];
  const float* bv    = (const float*)d_in[5];
  const float* Wt    = (const float*)d_in[6];
  const float* bt    = (const float*)d_in[7];
  const float* gamma = (const float*)d_in[8];
  const float* beta  = (const float*)d_in[9];
  float* out = (float*)d_out;

  // Arena (phase-overlaid). SZ = 4,194,304 elems; SZB = 16 MB. ws >= 128 MiB (verified R2).
  // [0,16M):  qT hi/lo       -> later U half0 [B][M][C]
  // [0,32M):  U [2][B][M][C] bf16 (after projections; qT dead)
  // [32,48M): y fp32 [B][C][N] (gemmt output)
  // [48,56M): xv bf16 TILED [B][64 nt][C][32 n]
  // [56M+):   wpack (Wv/Wt hi/lo), rowsum_g, csum[2], ssum/sqsum
  // [64M,66M): xT_hi [B][N][64]   [66M,68M): xT_lo
  // [72M,74M): xg [B][N][64] bf16
  // [78M+):    G' hi/lo [64][256]
  const size_t SZ = (size_t)NB * NC * SEQ;
  const size_t SZB = SZ * 4;
  char* wsb = (char*)d_ws;
  u16* qT_hi = (u16*)(wsb);
  u16* qT_lo = qT_hi + SZ;
  u16* Ua    = (u16*)(wsb);                 // [2][B][SEQ][NC]
  float* y   = (float*)(wsb + 2 * SZB);
  u16* xv    = (u16*)(wsb + 3 * SZB);
  u16* wpack = (u16*)(wsb + 3 * SZB + SZB / 2);
  u16* Wv_hi = wpack + 131072, *Wv_lo = wpack + 196608;
  u16* Wt_hi = wpack + 262144, *Wt_lo = wpack + 327680;
  float* rowsum_g = (float*)(wpack + 425984);     // [B][SEQ]
  float* csum = rowsum_g + (size_t)NB * SEQ;      // [2][B][SEQ]
  float* ssum = csum + 2 * (size_t)NB * SEQ;      // [256]
  float* sqsum = ssum + NC;                       // [256]
  u16* xT_hi = (u16*)(wsb + ((size_t)64 << 20));
  u16* xT_lo = (u16*)(wsb + ((size_t)66 << 20));
  u16* xg    = (u16*)(wsb + ((size_t)72 << 20));
  u16* Gp_hi = (u16*)(wsb + ((size_t)78 << 20));
  u16* Gp_lo = Gp_hi + 64 * 256;

  wconv_kernel<<<641, 256, 0, stream>>>(Wv, Wt, wpack, ssum, rowsum_g,
                                        Wq, Wk, Gp_hi, Gp_lo);
  tconv2_kernel<<<dim3(80, 64), 256, 0, stream>>>(q, x, qT_hi, qT_lo, xT_hi, xT_lo);

  const size_t shm256 = 64 * (256 + 8) * 2 * sizeof(u16);  // 67,584 B
  gemm_kernel<256><<<dim3(128, 4), 256, shm256, stream>>>(
      qT_hi, qT_lo, Wv_hi, Wv_lo, bv, xv);
  gemmxg_kernel<<<128, 256, 0, stream>>>(qT_hi, qT_lo, Gp_hi, Gp_lo, xg);

  rowsum_kernel<<<512, 256, 0, stream>>>(xg, xT_hi, xT_lo, rowsum_g);
  attn_kernel<<<512, 512, 0, stream>>>(xg, xT_hi, xT_lo, xv, rowsum_g, Ua, csum);
  gemmt_kernel<<<dim3(128, 4), 256, 0, stream>>>(
      Ua, csum, Wt_hi, Wt_lo, bt, y, ssum, sqsum);

  bnorm_kernel<<<4096, 256, 0, stream>>>(y, ssum, sqsum, gamma, beta, out);
}